// Round 2
// baseline (371.618 us; speedup 1.0000x reference)
//
#include <hip/hip_runtime.h>

typedef unsigned short u16;
typedef unsigned int u32;
typedef short bf16x8 __attribute__((ext_vector_type(8)));
typedef float f32x4 __attribute__((ext_vector_type(4)));

__device__ __forceinline__ float bf2f(u16 u){ return __uint_as_float(((u32)u)<<16); }
__device__ __forceinline__ u16 f2bf(float f){
  u32 x = __float_as_uint(f);
  x += 0x7fffu + ((x>>16)&1u);   // round-to-nearest-even
  return (u16)(x>>16);
}
__device__ __forceinline__ float ssq(u32 v){
  float a = bf2f((u16)(v&0xffffu)), b = bf2f((u16)(v>>16));
  return a*a + b*b;
}
__device__ __forceinline__ float ssq8(uint4 a, uint4 b){
  return ssq(a.x)+ssq(a.y)+ssq(a.z)+ssq(a.w)+ssq(b.x)+ssq(b.y)+ssq(b.z)+ssq(b.w);
}
__device__ __forceinline__ float gelu_exact(float x){
  return 0.5f*x*(1.f + erff(x*0.7071067811865475f));
}

// ---------------- transpose + cast fp32 W[K][N] -> bf16 WT[N][K] ----------------
__global__ __launch_bounds__(256) void transpose_cast(
    const float* __restrict__ w, u16* __restrict__ wt, int K, int N)
{
  __shared__ float t[32][33];
  int lx = threadIdx.x & 31, ly = threadIdx.x >> 5;
  int n0 = blockIdx.x*32, k0 = blockIdx.y*32;
  #pragma unroll
  for (int j=0;j<4;j++) t[ly+j*8][lx] = w[(long)(k0+ly+j*8)*N + n0+lx];
  __syncthreads();
  #pragma unroll
  for (int j=0;j<4;j++) wt[(long)(n0+ly+j*8)*K + k0+lx] = f2bf(t[lx][ly+j*8]);
}

// ---------------- layernorm fp32 row(768) -> bf16 ----------------
__global__ __launch_bounds__(256) void ln_rows(
    const float* __restrict__ x, const float* __restrict__ w, u16* __restrict__ out)
{
  int row = blockIdx.x, tid = threadIdx.x;
  const float* xr = x + (long)row*768;
  float v0 = xr[tid], v1 = xr[tid+256], v2 = xr[tid+512];
  float s = v0+v1+v2, sq = v0*v0+v1*v1+v2*v2;
  #pragma unroll
  for (int o=32;o>=1;o>>=1){ s += __shfl_down(s,o); sq += __shfl_down(sq,o); }
  __shared__ float red[8];
  int wv = tid>>6, ln = tid&63;
  if (ln==0){ red[wv]=s; red[wv+4]=sq; }
  __syncthreads();
  float S  = red[0]+red[1]+red[2]+red[3];
  float SQ = red[4]+red[5]+red[6]+red[7];
  float mu = S*(1.f/768.f);
  float var = SQ*(1.f/768.f) - mu*mu;
  float rstd = rsqrtf(var + 1e-5f);
  u16* o = out + (long)row*768;
  o[tid]     = f2bf((v0-mu)*rstd*w[tid]);
  o[tid+256] = f2bf((v1-mu)*rstd*w[tid+256]);
  o[tid+512] = f2bf((v2-mu)*rstd*w[tid+512]);
}

// ---------------- bf16 GEMM: C[M][N] = A[M][K] * W[K][N], W given as WT[N][K] ----------------
// EPI 0: store bf16; EPI 1: gelu -> bf16; EPI 2: fp32 store of resid + acc
template<int EPI>
__global__ __launch_bounds__(256) void gemm_bt(
    const u16* __restrict__ A, const u16* __restrict__ BT,
    int M, int N, int K,
    const float* __restrict__ resid, float* __restrict__ outF, u16* __restrict__ outB)
{
  constexpr int PAD = 40;               // 80B row stride: 16B aligned, 2-way max conflict
  __shared__ u16 As[128*PAD];
  __shared__ u16 Bs[128*PAD];
  int tid = threadIdx.x;
  int n0 = blockIdx.x*128, m0 = blockIdx.y*128;
  int w = tid>>6, lane = tid&63, lr = lane&15, lg = lane>>4;
  int wr = w>>1, wc = w&1;
  f32x4 acc[4][4];
  f32x4 z = {0.f,0.f,0.f,0.f};
  #pragma unroll
  for (int m=0;m<4;m++)
    #pragma unroll
    for (int n=0;n<4;n++) acc[m][n] = z;
  int sr = tid>>1, sh = tid&1;
  const u16* Ag = A  + (long)(m0+sr)*K + sh*16;
  const u16* Bg = BT + (long)(n0+sr)*K + sh*16;
  u16* Asw = &As[sr*PAD + sh*16];
  u16* Bsw = &Bs[sr*PAD + sh*16];
  for (int k0=0; k0<K; k0+=32){
    uint4 a0 = *(const uint4*)(Ag + k0);
    uint4 a1 = *(const uint4*)(Ag + k0 + 8);
    uint4 b0 = *(const uint4*)(Bg + k0);
    uint4 b1 = *(const uint4*)(Bg + k0 + 8);
    *(uint4*)Asw = a0; *(uint4*)(Asw+8) = a1;
    *(uint4*)Bsw = b0; *(uint4*)(Bsw+8) = b1;
    __syncthreads();
    bf16x8 af[4], bfr[4];
    #pragma unroll
    for (int m=0;m<4;m++) af[m]  = *(const bf16x8*)&As[(wr*64+m*16+lr)*PAD + lg*8];
    #pragma unroll
    for (int n=0;n<4;n++) bfr[n] = *(const bf16x8*)&Bs[(wc*64+n*16+lr)*PAD + lg*8];
    #pragma unroll
    for (int m=0;m<4;m++)
      #pragma unroll
      for (int n=0;n<4;n++)
        acc[m][n] = __builtin_amdgcn_mfma_f32_16x16x32_bf16(af[m], bfr[n], acc[m][n], 0,0,0);
    __syncthreads();
  }
  #pragma unroll
  for (int m=0;m<4;m++)
    #pragma unroll
    for (int n=0;n<4;n++)
      #pragma unroll
      for (int r=0;r<4;r++){
        int row = m0 + wr*64 + m*16 + lg*4 + r;   // C/D layout: row=(lane>>4)*4+reg, col=lane&15
        int col = n0 + wc*64 + n*16 + lr;
        long idx = (long)row*N + col;
        float v = acc[m][n][r];
        if (EPI==0)      outB[idx] = f2bf(v);
        else if (EPI==1) outB[idx] = f2bf(gelu_exact(v));
        else             outF[idx] = resid[idx] + v;
      }
}

// ---------------- fused causal exp(-sqL2/16) attention ----------------
// qkv: [B*T][2304] bf16 (q|k|v each 768).  Y: [B*T][768] bf16.
__global__ __launch_bounds__(256) void attn_fused(
    const u16* __restrict__ qkv, u16* __restrict__ Y, int T, int nqt)
{
  constexpr int C3=2304, C=768, PAD=72;   // 144B row stride: 16B aligned, 2-way max conflict
  __shared__ u16 Qs[64*PAD], Ks[64*PAD], VTs[64*PAD], Ps[64*PAD];
  __shared__ float q2s[64], k2s[64];
  int bz = blockIdx.x;
  int qt = bz % nqt; int h = (bz/nqt) % 12; int b = bz/(nqt*12);
  int tid = threadIdx.x, w = tid>>6, lane = tid&63, lr = lane&15, lg = lane>>4;
  int q0 = qt*64;
  int r = tid>>2, cg = tid&3;
  long base = (long)(b*T);
  { // stage Q tile (once) + q2 from the same bf16 values
    const u16* src = qkv + (base + q0 + r)*C3 + h*64 + cg*16;
    uint4 v0 = *(const uint4*)src;
    uint4 v1 = *(const uint4*)(src+8);
    *(uint4*)&Qs[r*PAD + cg*16]     = v0;
    *(uint4*)&Qs[r*PAD + cg*16 + 8] = v1;
    float p = ssq8(v0, v1);
    p += __shfl_xor(p,1); p += __shfl_xor(p,2);
    if (cg==0) q2s[r] = p;
  }
  f32x4 accY[4];
  f32x4 z = {0.f,0.f,0.f,0.f};
  #pragma unroll
  for (int i=0;i<4;i++) accY[i]=z;

  for (int kt=0; kt<=qt; ++kt){
    int k0 = kt*64;
    { // stage K + k2
      const u16* src = qkv + (base + k0 + r)*C3 + C + h*64 + cg*16;
      uint4 v0 = *(const uint4*)src; uint4 v1 = *(const uint4*)(src+8);
      *(uint4*)&Ks[r*PAD + cg*16]     = v0;
      *(uint4*)&Ks[r*PAD + cg*16 + 8] = v1;
      float p = ssq8(v0, v1);
      p += __shfl_xor(p,1); p += __shfl_xor(p,2);
      if (cg==0) k2s[r] = p;
    }
    { // stage V transposed: VTs[d][k]
      const u16* src = qkv + (base + k0 + r)*C3 + 2*C + h*64 + cg*16;
      uint4 v0 = *(const uint4*)src; uint4 v1 = *(const uint4*)(src+8);
      u32 vv[8] = {v0.x,v0.y,v0.z,v0.w,v1.x,v1.y,v1.z,v1.w};
      #pragma unroll
      for (int i=0;i<8;i++){
        VTs[(cg*16+2*i  )*PAD + r] = (u16)(vv[i]&0xffffu);
        VTs[(cg*16+2*i+1)*PAD + r] = (u16)(vv[i]>>16);
      }
    }
    __syncthreads();
    // S = Q K^T  (wave w owns q rows [w*16, w*16+16))
    bf16x8 aq0 = *(const bf16x8*)&Qs[(w*16+lr)*PAD + lg*8];
    bf16x8 aq1 = *(const bf16x8*)&Qs[(w*16+lr)*PAD + 32 + lg*8];
    #pragma unroll
    for (int nf=0;nf<4;nf++){
      bf16x8 b0 = *(const bf16x8*)&Ks[(nf*16+lr)*PAD + lg*8];
      bf16x8 b1 = *(const bf16x8*)&Ks[(nf*16+lr)*PAD + 32 + lg*8];
      f32x4 s = z;
      s = __builtin_amdgcn_mfma_f32_16x16x32_bf16(aq0, b0, s, 0,0,0);
      s = __builtin_amdgcn_mfma_f32_16x16x32_bf16(aq1, b1, s, 0,0,0);
      int kl = nf*16 + lr;
      float k2v = k2s[kl];
      #pragma unroll
      for (int rr=0;rr<4;rr++){
        int q = w*16 + lg*4 + rr;
        float e = __expf(0.125f*s[rr] - 0.0625f*(q2s[q] + k2v));
        if (kt==qt && kl > q) e = 0.f;            // causal (tiles share diagonal offset)
        Ps[q*PAD + kl] = f2bf(e);
      }
    }
    __syncthreads();
    // Y += P V
    bf16x8 ap0 = *(const bf16x8*)&Ps[(w*16+lr)*PAD + lg*8];
    bf16x8 ap1 = *(const bf16x8*)&Ps[(w*16+lr)*PAD + 32 + lg*8];
    #pragma unroll
    for (int nf=0;nf<4;nf++){
      bf16x8 v0 = *(const bf16x8*)&VTs[(nf*16+lr)*PAD + lg*8];
      bf16x8 v1 = *(const bf16x8*)&VTs[(nf*16+lr)*PAD + 32 + lg*8];
      accY[nf] = __builtin_amdgcn_mfma_f32_16x16x32_bf16(ap0, v0, accY[nf], 0,0,0);
      accY[nf] = __builtin_amdgcn_mfma_f32_16x16x32_bf16(ap1, v1, accY[nf], 0,0,0);
    }
    __syncthreads();
  }
  #pragma unroll
  for (int nf=0;nf<4;nf++)
    #pragma unroll
    for (int rr=0;rr<4;rr++){
      int q = w*16 + lg*4 + rr;
      Y[(base + q0 + q)*C + h*64 + nf*16 + lr] = f2bf(accY[nf][rr]);
    }
}

extern "C" void kernel_launch(void* const* d_in, const int* in_sizes, int n_in,
                              void* d_out, int out_size, void* d_ws, size_t ws_size,
                              hipStream_t stream)
{
  (void)in_sizes; (void)n_in; (void)out_size; (void)ws_size;
  const float* x      = (const float*)d_in[0];
  const float* w_ln1  = (const float*)d_in[1];
  const float* w_attn = (const float*)d_in[2];
  const float* w_ap   = (const float*)d_in[3];
  const float* w_ln2  = (const float*)d_in[4];
  const float* w_fc   = (const float*)d_in[5];
  const float* w_mlp  = (const float*)d_in[6];
  float* out = (float*)d_out;
  const int M = 4096, T = 2048;   // B=2, T=2048, C=768 fixed by the problem

  // workspace layout (bf16 elems unless noted); h reuses qkv+Ybuf (both dead by then)
  u16* ws      = (u16*)d_ws;
  u16* wT_attn = ws;                      // 2304*768
  u16* wT_ap   = wT_attn + 2304*768;      // 768*768
  u16* wT_fc   = wT_ap   + 768*768;       // 3072*768
  u16* wT_mlp  = wT_fc   + 3072*768;      // 768*3072
  u16* xln     = wT_mlp  + 768*3072;      // 4096*768
  u16* qkvb    = xln     + 4096*768;      // 4096*2304
  u16* Ybuf    = qkvb    + 4096*2304;     // 4096*768
  u16* hbuf    = qkvb;                    // 4096*3072 aliases qkv|Ybuf (exact fit)
  float* x2    = (float*)(Ybuf + 4096*768); // 4096*768 fp32

  dim3 blk(256);
  transpose_cast<<<dim3(2304/32,  768/32), blk, 0, stream>>>(w_attn, wT_attn,  768, 2304);
  transpose_cast<<<dim3( 768/32,  768/32), blk, 0, stream>>>(w_ap,   wT_ap,    768,  768);
  transpose_cast<<<dim3(3072/32,  768/32), blk, 0, stream>>>(w_fc,   wT_fc,    768, 3072);
  transpose_cast<<<dim3( 768/32, 3072/32), blk, 0, stream>>>(w_mlp,  wT_mlp,  3072,  768);

  ln_rows<<<dim3(M), blk, 0, stream>>>(x, w_ln1, xln);
  gemm_bt<0><<<dim3(2304/128, M/128), blk, 0, stream>>>(xln, wT_attn, M, 2304, 768, nullptr, nullptr, qkvb);
  attn_fused<<<dim3(2*12*(T/64)), blk, 0, stream>>>(qkvb, Ybuf, T, T/64);
  gemm_bt<2><<<dim3( 768/128, M/128), blk, 0, stream>>>(Ybuf, wT_ap, M, 768, 768, x, x2, nullptr);
  ln_rows<<<dim3(M), blk, 0, stream>>>(x2, w_ln2, xln);
  gemm_bt<1><<<dim3(3072/128, M/128), blk, 0, stream>>>(xln, wT_fc, M, 3072, 768, nullptr, nullptr, hbuf);
  gemm_bt<2><<<dim3( 768/128, M/128), blk, 0, stream>>>(hbuf, wT_mlp, M, 768, 3072, x2, out, nullptr);
}